// Round 1
// baseline (476.246 us; speedup 1.0000x reference)
//
#include <hip/hip_runtime.h>
#include <hip/hip_bf16.h>

#define B_  16
#define S_  1024
#define H_  768
#define NH_ 12
#define HD_ 64
#define BS_ (B_*S_)   // 16384
#define WROWS_ 589824 // 768*768 per weight matrix

typedef __bf16 bfx8 __attribute__((ext_vector_type(8)));
typedef __bf16 bfx4 __attribute__((ext_vector_type(4)));
typedef float  f32x4 __attribute__((ext_vector_type(4)));

#define MFMA(a,b,c) __builtin_amdgcn_mfma_f32_16x16x32_bf16(a,b,c,0,0,0)

__device__ __forceinline__ float fast_exp2(float x) {
#if __has_builtin(__builtin_amdgcn_exp2f)
    return __builtin_amdgcn_exp2f(x);
#else
    return exp2f(x);
#endif
}

// async global->LDS, 16B per lane; LDS dest = wave-uniform base + lane*16
__device__ __forceinline__ void async_cp16(const __bf16* g, __bf16* l) {
    __builtin_amdgcn_global_load_lds(
        (const __attribute__((address_space(1))) unsigned int*)g,
        (__attribute__((address_space(3))) unsigned int*)l,
        16, 0, 0);
}

#define LOG2E 1.4426950408889634f
#define C1    (0.125f * LOG2E)     // score scale folded with log2(e)
#define SMAX  12.0f                // static softmax offset (exp2 domain)

// ---------------------------------------------------------------------------
// Pre-cast: hidden fp32 -> bf16 (hbf), [qw|kw|vw|ow] fp32 -> bf16 (wbuf).
// ---------------------------------------------------------------------------
__global__ __launch_bounds__(256) void precast(
    const float* __restrict__ hidden,
    const float* __restrict__ qw, const float* __restrict__ kw,
    const float* __restrict__ vw, const float* __restrict__ ow,
    __bf16* __restrict__ hbf, __bf16* __restrict__ wbuf)
{
    const int tid = threadIdx.x;
    const int bid = blockIdx.x;
    if (bid < 6144) {
        const long base = ((long)bid * 256 + tid) * 8;
        f32x4 a = *(const f32x4*)(hidden + base);
        f32x4 b = *(const f32x4*)(hidden + base + 4);
        bfx8 o;
        #pragma unroll
        for (int j = 0; j < 4; ++j) { o[j] = (__bf16)a[j]; o[4 + j] = (__bf16)b[j]; }
        *(bfx8*)(hbf + base) = o;
    } else {
        const long e = ((long)(bid - 6144) * 256 + tid) * 8;
        const int kind = (int)(e / WROWS_);
        const float* src = kind == 0 ? qw : kind == 1 ? kw : kind == 2 ? vw : ow;
        const long off = e - (long)kind * WROWS_;
        f32x4 a = *(const f32x4*)(src + off);
        f32x4 b = *(const f32x4*)(src + off + 4);
        bfx8 o;
        #pragma unroll
        for (int j = 0; j < 4; ++j) { o[j] = (__bf16)a[j]; o[4 + j] = (__bf16)b[j]; }
        *(bfx8*)(wbuf + e) = o;
    }
}

// ---------------------------------------------------------------------------
// Fused QKV GEMM. 128x128 tile, BK=64, swizzled global_load_lds staging.
// (unchanged this round)
// ---------------------------------------------------------------------------
__global__ __launch_bounds__(512, 4) void qkv_gemm(
    const __bf16* __restrict__ hbf, const __bf16* __restrict__ wbuf,
    const float* __restrict__ qb, const float* __restrict__ kb,
    const float* __restrict__ vb,
    __bf16* __restrict__ qo, __bf16* __restrict__ ko, __bf16* __restrict__ vto)
{
    __shared__ __bf16 smem[18432];      // 36864 B: As|Bs in [0,16384), Ts all
    __bf16* As = smem;                  // 8192 elems
    __bf16* Bs = smem + 8192;           // 8192 elems
    __bf16* Ts = smem;                  // epilogue: 8 waves x 2304 elems

    const int bid  = blockIdx.x;
    const int xcd  = bid & 7;
    const int slot = bid >> 3;          // 0..287
    const int xx   = slot >> 4;         // 0..17  (n-tile / weight panel)
    const int yy   = xcd * 16 + (slot & 15);   // 0..127 (m-tile)

    const int tid  = threadIdx.x;
    const int lane = tid & 63, wid = tid >> 6;
    const int quad = lane >> 4, l16 = lane & 15;
    const int n0g = xx * 128;
    const int m0  = yy * 128;
    const int wm = (wid & 3) * 32;      // s-slice (4)
    const int wn = (wid >> 2) * 64;     // d-slice (2)
    const int kind = xx / 6;            // 0=Q,1=K,2=V
    const int nl0  = n0g - kind * 768;

    // acc: Q/K -> [dt][st] flat dt*2+st ; V -> [st][dt] flat st*4+dt
    f32x4 acc[8];
    #pragma unroll
    for (int i = 0; i < 8; ++i)
        #pragma unroll
        for (int r = 0; r < 4; ++r) acc[i][r] = 0.0f;

    const int drow = lane >> 3;
    const int dcol = ((lane & 7) ^ (drow & 7)) * 8;
    const __bf16* Ag0 = hbf  + (long)(m0  + drow) * H_ + dcol;
    const __bf16* Bg0 = wbuf + (long)(n0g + drow) * H_ + dcol;
    const int swz = (l16 & 7);

    for (int kt = 0; kt < 12; ++kt) {
        __syncthreads();
        const int k0 = kt * 64;
        #pragma unroll
        for (int c = 0; c < 2; ++c) {
            const int cc = wid * 2 + c;       // chunk 0..15 (8 rows each)
            async_cp16(Ag0 + (long)cc * 8 * H_ + k0, As + cc * 512);
            async_cp16(Bg0 + (long)cc * 8 * H_ + k0, Bs + cc * 512);
        }
        __syncthreads();
        #pragma unroll
        for (int ks = 0; ks < 2; ++ks) {
            const int coff = ((ks * 4 + quad) ^ swz) * 8;
            bfx8 af[2], bb[4];
            #pragma unroll
            for (int t = 0; t < 2; ++t)
                af[t] = *(const bfx8*)(As + (wm + t * 16 + l16) * 64 + coff);
            #pragma unroll
            for (int t = 0; t < 4; ++t)
                bb[t] = *(const bfx8*)(Bs + (wn + t * 16 + l16) * 64 + coff);
            if (kind < 2) {
                #pragma unroll
                for (int dt = 0; dt < 4; ++dt)
                    #pragma unroll
                    for (int st = 0; st < 2; ++st)
                        acc[dt * 2 + st] = MFMA(bb[dt], af[st], acc[dt * 2 + st]);
            } else {
                #pragma unroll
                for (int st = 0; st < 2; ++st)
                    #pragma unroll
                    for (int dt = 0; dt < 4; ++dt)
                        acc[st * 4 + dt] = MFMA(af[st], bb[dt], acc[st * 4 + dt]);
            }
        }
    }

    __syncthreads();                    // As/Bs dead -> Ts reuse safe
    const int b  = m0 >> 10;
    const int hq = (nl0 + wn) >> 6;
    const int s_base = (m0 & 1023) + wm;

    if (kind < 2) {
        __bf16* Tw = Ts + wid * 2304;   // 32 x 72 tile [s][d]
        const float* bias = (kind == 0) ? qb : kb;
        __bf16* outp = (kind == 0) ? qo : ko;
        // acc[dt*2+st]: row=d=dt*16+quad*4+r, col=s=st*16+l16
        #pragma unroll
        for (int dt = 0; dt < 4; ++dt) {
            f32x4 bv = *(const f32x4*)(bias + nl0 + wn + dt * 16 + quad * 4);
            #pragma unroll
            for (int st = 0; st < 2; ++st) {
                bfx4 pk;
                #pragma unroll
                for (int r = 0; r < 4; ++r)
                    pk[r] = (__bf16)(acc[dt * 2 + st][r] + bv[r]);
                *(bfx4*)(Tw + (st * 16 + l16) * 72 + dt * 16 + quad * 4) = pk;
            }
        }
        __bf16* op = outp + ((((long)(b * NH_ + hq)) << 10) + s_base) * HD_;
        const int srow = lane >> 3, c8 = (lane & 7) * 8;
        #pragma unroll
        for (int i = 0; i < 4; ++i) {
            const int row = i * 8 + srow;                     // 0..31
            bfx8 vv = *(const bfx8*)(Tw + row * 72 + c8);
            *(bfx8*)(op + row * HD_ + c8) = vv;               // 1KB linear/instr
        }
    } else {
        __bf16* Tw = Ts + wid * 2304;   // 64 x 36 tile [d][s]
        // acc[st*4+dt]: row=s=st*16+quad*4+r, col=d=dt*16+l16
        #pragma unroll
        for (int dt = 0; dt < 4; ++dt) {
            const float bv = vb[nl0 + wn + dt * 16 + l16];
            #pragma unroll
            for (int st = 0; st < 2; ++st) {
                bfx4 pk;
                #pragma unroll
                for (int r = 0; r < 4; ++r)
                    pk[r] = (__bf16)(acc[st * 4 + dt][r] + bv);
                *(bfx4*)(Tw + (dt * 16 + l16) * 36 + st * 16 + quad * 4) = pk;
            }
        }
        __bf16* op = vto + (((long)(b * NH_ + hq) * HD_) << 10);
        #pragma unroll
        for (int i = 0; i < 4; ++i) {
            const int d = i * 16 + (lane >> 2);
            const int s8 = (lane & 3) * 8;
            bfx8 vv = *(const bfx8*)(Tw + d * 36 + s8);
            *(bfx8*)(op + ((long)d << 10) + s_base + s8) = vv;
        }
    }
}

// ---------------------------------------------------------------------------
// Attention, S^T formulation. Round 6 restructure:
//  - 64-key K/V tiles, double-buffered: DMA for kt+1 issued right after the
//    barrier, compute on buf[kt&1] hides the vmcnt(0) drain at the next
//    barrier (no more sync->DMA->sync serial stage).
//  - Ps shrunk 32x72 -> 32x32 per wave (P produced/consumed in 32-key
//    halves), 16B-group XOR swizzle (slot = g ^ (row&3)) -> conflict-free
//    bfx4 writes and bfx8 reads (was 8-way on the stride-72 layout).
//  - LDS 73728 -> 53248 B => 3 blocks/CU = exactly grid/256; launch_bounds
//    (512,6) keeps regs <= 85 so all 24 waves/CU are resident.
// ---------------------------------------------------------------------------
__global__ __launch_bounds__(512, 6) void attn_kernel(
    const __bf16* __restrict__ q, const __bf16* __restrict__ k,
    const __bf16* __restrict__ vT, const float* __restrict__ mask,
    __bf16* __restrict__ ctx)
{
    __shared__ __bf16 Ks[2][4096];      // [buf][64 keys x 64 d]    16 KB
    __shared__ __bf16 Vs[2][4096];      // [buf][64 d x 64 keys]    16 KB
    __shared__ __bf16 Ps[8][1024];      // per-wave [32 q][32 k] swz 16 KB
    __shared__ float  Ms[1024];         // mask*log2e - SMAX          4 KB

    const int tid  = threadIdx.x;
    const int lane = tid & 63, wid = tid >> 6;
    const int quad = lane >> 4, l16 = lane & 15;
    const int qc = blockIdx.x, h = blockIdx.y, b = blockIdx.z;

    const long base = ((long)(b * NH_ + h)) << 16;   // * S_ * HD_
    const __bf16* qh = q  + base;
    const __bf16* kh = k  + base;
    const __bf16* vh = vT + base;
    const float*  mb = mask + b * S_;

    Ms[tid]       = mb[tid]       * LOG2E - SMAX;
    Ms[tid + 512] = mb[tid + 512] * LOG2E - SMAX;

    const int qrow_base = qc * 256 + wid * 32;
    bfx8 qf[2][2];
    #pragma unroll
    for (int nt = 0; nt < 2; ++nt)
        #pragma unroll
        for (int kk = 0; kk < 2; ++kk)
            qf[nt][kk] = *(const bfx8*)(qh + (qrow_base + nt * 16 + l16) * HD_ +
                                        kk * 32 + quad * 8);

    f32x4 o[4][2];
    f32x4 lacc[2];
    #pragma unroll
    for (int mt = 0; mt < 4; ++mt)
        #pragma unroll
        for (int nt = 0; nt < 2; ++nt)
            #pragma unroll
            for (int r = 0; r < 4; ++r) o[mt][nt][r] = 0.0f;
    #pragma unroll
    for (int nt = 0; nt < 2; ++nt)
        #pragma unroll
        for (int r = 0; r < 4; ++r) lacc[nt][r] = 0.0f;

    // staging geometry: chunk = wid (1KB), 8 rows/chunk, row-local swizzle
    const int r8  = lane >> 3;                 // row within chunk (0..7)
    const int c8  = ((lane & 7) ^ r8) * 8;     // pre-swizzled 16B col group
    const int swz = l16 & 7;

    // prologue: stage kt=0 into buf 0
    async_cp16(kh + (long)(wid * 8 + r8) * HD_ + c8, &Ks[0][wid * 512]);
    async_cp16(vh + (long)(wid * 8 + r8) * S_  + c8, &Vs[0][wid * 512]);

    for (int kt = 0; kt < 16; ++kt) {
        __syncthreads();                // per-wave vmcnt(0): buf[kt&1] ready
        const __bf16* Kb = Ks[kt & 1];
        const __bf16* Vb = Vs[kt & 1];
        if (kt < 15) {                  // prefetch kt+1 into the other buffer
            const int kn = kt + 1;
            async_cp16(kh + (long)(kn * 64 + wid * 8 + r8) * HD_ + c8,
                       &Ks[kn & 1][wid * 512]);
            async_cp16(vh + (long)(wid * 8 + r8) * S_ + kn * 64 + c8,
                       &Vs[kn & 1][wid * 512]);
        }

        #pragma unroll
        for (int ph = 0; ph < 2; ++ph) {        // 32-key half
            #pragma unroll
            for (int tl = 0; tl < 2; ++tl) {    // 16-key score tile
                const int t = ph * 2 + tl;
                f32x4 sc[2];
                #pragma unroll
                for (int nt = 0; nt < 2; ++nt)
                    #pragma unroll
                    for (int r = 0; r < 4; ++r) sc[nt][r] = 0.0f;
                #pragma unroll
                for (int kk = 0; kk < 2; ++kk) {
                    bfx8 kf = *(const bfx8*)(Kb + (t * 16 + l16) * 64 +
                                             ((kk * 4 + quad) ^ swz) * 8);
                    #pragma unroll
                    for (int nt = 0; nt < 2; ++nt)
                        sc[nt] = MFMA(kf, qf[nt][kk], sc[nt]);
                }
                const f32x4 mv = *(const f32x4*)(&Ms[kt * 64 + t * 16 + quad * 4]);
                // logical key group g = tl*2 + (quad>>1); slot = g ^ (row&3)
                const int pslot = ((tl * 2 + (quad >> 1)) ^ (l16 & 3)) * 8 +
                                  (quad & 1) * 4;
                #pragma unroll
                for (int nt = 0; nt < 2; ++nt) {
                    f32x4 p; bfx4 pb;
                    #pragma unroll
                    for (int r = 0; r < 4; ++r)
                        p[r] = fast_exp2(sc[nt][r] * C1 + mv[r]);
                    lacc[nt] += p;
                    #pragma unroll
                    for (int r = 0; r < 4; ++r) pb[r] = (__bf16)p[r];
                    *(bfx4*)(&Ps[wid][(nt * 16 + l16) * 32 + pslot]) = pb;
                }
            }
            // PV for this 32-key half: logical group g = quad, slot g^(row&3)
            bfx8 pf[2];
            const int prslot = (quad ^ (l16 & 3)) * 8;
            #pragma unroll
            for (int nt = 0; nt < 2; ++nt)
                pf[nt] = *(const bfx8*)(&Ps[wid][(nt * 16 + l16) * 32 + prslot]);
            const int vcg = (ph * 4 + quad) ^ swz;
            #pragma unroll
            for (int mt = 0; mt < 4; ++mt) {
                bfx8 vf = *(const bfx8*)(Vb + (mt * 16 + l16) * 64 + vcg * 8);
                #pragma unroll
                for (int nt = 0; nt < 2; ++nt)
                    o[mt][nt] = MFMA(vf, pf[nt], o[mt][nt]);
            }
        }
    }

    float linv[2];
    #pragma unroll
    for (int nt = 0; nt < 2; ++nt) {
        float s = lacc[nt][0] + lacc[nt][1] + lacc[nt][2] + lacc[nt][3];
        s += __shfl_xor(s, 16);
        s += __shfl_xor(s, 32);
        linv[nt] = 1.0f / s;
    }

    #pragma unroll
    for (int nt = 0; nt < 2; ++nt) {
        #pragma unroll
        for (int mt = 0; mt < 4; ++mt) {
            bfx4 ov;
            #pragma unroll
            for (int r = 0; r < 4; ++r)
                ov[r] = (__bf16)(o[mt][nt][r] * linv[nt]);
            const int qrow = qrow_base + nt * 16 + l16;
            *(bfx4*)(ctx + ((long)(b << 10) + qrow) * H_ + h * HD_ +
                     mt * 16 + quad * 4) = ov;
        }
    }
}

// ---------------------------------------------------------------------------
// Output projection + residual. 8 waves x (32m x 64n), XCD-chunked map.
// ---------------------------------------------------------------------------
__global__ __launch_bounds__(512, 4) void out_gemm(
    const __bf16* __restrict__ ctx, const __bf16* __restrict__ wbuf,
    const float* __restrict__ ob, const float* __restrict__ hidden,
    float* __restrict__ xres)
{
    __shared__ __bf16 As[128 * 64];
    __shared__ __bf16 Bs[128 * 64];

    const int bid  = blockIdx.x;
    const int xcd  = bid & 7;
    const int slot = bid >> 3;          // 0..95
    const int xx   = slot >> 4;         // 0..5
    const int yy   = xcd * 16 + (slot & 15);

    const int tid  = threadIdx.x;
    const int lane = tid & 63, wid = tid >> 6;
    const int quad = lane >> 4, l16 = lane & 15;
    const int n0 = xx * 128;
    const int m0 = yy * 128;
    const int wm = (wid & 3) * 32;
    const int wn = (wid >> 2) * 64;

    f32x4 acc[2][4];
    #pragma unroll
    for (int i = 0; i < 2; ++i)
        #pragma unroll
        for (int j = 0; j < 4; ++j)
            #pragma unroll
            for (int r = 0; r < 4; ++r) acc[i][j][r] = 0.0f;

    const int drow = lane >> 3;
    const int dcol = ((lane & 7) ^ (drow & 7)) * 8;
    const __bf16* Ag0 = ctx  + (long)(m0 + drow) * H_ + dcol;
    const __bf16* Bg0 = wbuf + (long)(3 * 768 + n0 + drow) * H_ + dcol;
    const int swz = (l16 & 7);

    for (int kt = 0; kt < 12; ++kt) {
        __syncthreads();
        const int k0 = kt * 64;
        #pragma unroll
        for (int c = 0; c < 2; ++c) {
            const int cc = wid * 2 + c;
            async_cp16(Ag0 + (long)cc * 8 * H_ + k0, As + cc * 512);
            async_cp16(Bg0 + (long)cc * 8 * H_ + k0, Bs + cc * 512);
        }
        __syncthreads();
        #pragma unroll
        for (int ks = 0; ks < 2; ++ks) {
            const int coff = ((ks * 4 + quad) ^ swz) * 8;
            bfx8 af[2], bb[4];
            #pragma unroll
            for (int t = 0; t < 2; ++t)
                af[t] = *(const bfx8*)(As + (wm + t * 16 + l16) * 64 + coff);
            #pragma unroll
            for (int t = 0; t < 4; ++t)
                bb[t] = *(const bfx8*)(Bs + (wn + t * 16 + l16) * 64 + coff);
            #pragma unroll
            for (int mt = 0; mt < 2; ++mt)
                #pragma unroll
                for (int nt = 0; nt < 4; ++nt)
                    acc[mt][nt] = MFMA(af[mt], bb[nt], acc[mt][nt]);
        }
    }

    #pragma unroll
    for (int nt = 0; nt < 4; ++nt) {
        const int n = n0 + wn + nt * 16 + l16;
        const float bv = ob[n];
        #pragma unroll
        for (int mt = 0; mt < 2; ++mt) {
            #pragma unroll
            for (int r = 0; r < 4; ++r) {
                const int m = m0 + wm + mt * 16 + quad * 4 + r;
                const long idx = (long)m * H_ + n;
                xres[idx] = acc[mt][nt][r] + bv + hidden[idx];
            }
        }
    }
}

// ---------------------------------------------------------------------------
// LayerNorm over H=768, wave per row
// ---------------------------------------------------------------------------
__global__ __launch_bounds__(256) void ln_kernel(
    const float* __restrict__ xres, const float* __restrict__ gamma,
    const float* __restrict__ beta, float* __restrict__ out)
{
    const int tid = threadIdx.x, lane = tid & 63, wid = tid >> 6;
    const long row = (long)blockIdx.x * 4 + wid;
    const float* xr = xres + row * H_;

    f32x4 xv[3];
    float sum = 0.0f, sumsq = 0.0f;
    #pragma unroll
    for (int c = 0; c < 3; ++c) {
        xv[c] = *(const f32x4*)(xr + c * 256 + lane * 4);
        #pragma unroll
        for (int j = 0; j < 4; ++j) { sum += xv[c][j]; sumsq += xv[c][j] * xv[c][j]; }
    }
    #pragma unroll
    for (int off = 1; off < 64; off <<= 1) {
        sum   += __shfl_xor(sum, off);
        sumsq += __shfl_xor(sumsq, off);
    }
    const float mean = sum * (1.0f / 768.0f);
    const float var  = sumsq * (1.0f / 768.0f) - mean * mean;
    const float rstd = rsqrtf(var + 1e-12f);

    float* orow = out + row * H_;
    #pragma unroll
    for (int c = 0; c < 3; ++c) {
        f32x4 g  = *(const f32x4*)(gamma + c * 256 + lane * 4);
        f32x4 bt = *(const f32x4*)(beta  + c * 256 + lane * 4);
        f32x4 ov;
        #pragma unroll
        for (int j = 0; j < 4; ++j) ov[j] = (xv[c][j] - mean) * rstd * g[j] + bt[j];
        *(f32x4*)(orow + c * 256 + lane * 4) = ov;
    }
}

extern "C" void kernel_launch(void* const* d_in, const int* in_sizes, int n_in,
                              void* d_out, int out_size, void* d_ws, size_t ws_size,
                              hipStream_t stream)
{
    const float* hidden = (const float*)d_in[0];
    const float* mask   = (const float*)d_in[1];
    const float* qw = (const float*)d_in[2];
    const float* qb = (const float*)d_in[3];
    const float* kw = (const float*)d_in[4];
    const float* kb = (const float*)d_in[5];
    const float* vw = (const float*)d_in[6];
    const float* vb = (const float*)d_in[7];
    const float* ow = (const float*)d_in[8];
    const float* ob = (const float*)d_in[9];
    const float* gamma = (const float*)d_in[10];
    const float* beta  = (const float*)d_in[11];
    float* out = (float*)d_out;

    // ws layout (96 MB): [0,24) hbf->ctx alias; [24,48) q; [48,72) k; [72,96) vt
    // xres fp32 aliases [24,72). wbuf bf16 weights live in d_out until ln.
    char* ws = (char*)d_ws;
    const size_t SZB = (size_t)BS_ * H_ * 2;     // 25,165,824 B per bf16 buffer
    __bf16* hbf  = (__bf16*)ws;
    __bf16* qws  = (__bf16*)(ws + SZB);
    __bf16* kws  = (__bf16*)(ws + 2 * SZB);
    __bf16* vtws = (__bf16*)(ws + 3 * SZB);
    __bf16* cws  = hbf;                          // ctx aliases hbf
    float*  xres = (float*)(ws + SZB);           // aliases q,k
    __bf16* wbuf = (__bf16*)d_out;               // scratch inside output buffer

    precast<<<dim3(7296), 256, 0, stream>>>(hidden, qw, kw, vw, ow, hbf, wbuf);
    qkv_gemm<<<dim3(2304), 512, 0, stream>>>(hbf, wbuf, qb, kb, vb,
                                             qws, kws, vtws);
    attn_kernel<<<dim3(4, 12, 16), 512, 0, stream>>>(qws, kws, vtws, mask, cws);
    out_gemm<<<dim3(768), 512, 0, stream>>>(cws, wbuf, ob, hidden, xres);
    ln_kernel<<<dim3(4096), 256, 0, stream>>>(xres, gamma, beta, out);
}

// Round 2
// 308.112 us; speedup vs baseline: 1.5457x; 1.5457x over previous
//
#include <hip/hip_runtime.h>
#include <hip/hip_bf16.h>

#define B_  16
#define S_  1024
#define H_  768
#define NH_ 12
#define HD_ 64
#define BS_ (B_*S_)   // 16384
#define WROWS_ 589824 // 768*768 per weight matrix

typedef __bf16 bfx8 __attribute__((ext_vector_type(8)));
typedef __bf16 bfx4 __attribute__((ext_vector_type(4)));
typedef float  f32x4 __attribute__((ext_vector_type(4)));

#define MFMA(a,b,c) __builtin_amdgcn_mfma_f32_16x16x32_bf16(a,b,c,0,0,0)

__device__ __forceinline__ float fast_exp2(float x) {
#if __has_builtin(__builtin_amdgcn_exp2f)
    return __builtin_amdgcn_exp2f(x);
#else
    return exp2f(x);
#endif
}

// async global->LDS, 16B per lane; LDS dest = wave-uniform base + lane*16
__device__ __forceinline__ void async_cp16(const __bf16* g, __bf16* l) {
    __builtin_amdgcn_global_load_lds(
        (const __attribute__((address_space(1))) unsigned int*)g,
        (__attribute__((address_space(3))) unsigned int*)l,
        16, 0, 0);
}

#define LOG2E 1.4426950408889634f
#define C1    (0.125f * LOG2E)     // score scale folded with log2(e)
#define SMAX  12.0f                // static softmax offset (exp2 domain)

// ---------------------------------------------------------------------------
// Pre-cast: hidden fp32 -> bf16 (hbf), [qw|kw|vw|ow] fp32 -> bf16 (wbuf).
// ---------------------------------------------------------------------------
__global__ __launch_bounds__(256) void precast(
    const float* __restrict__ hidden,
    const float* __restrict__ qw, const float* __restrict__ kw,
    const float* __restrict__ vw, const float* __restrict__ ow,
    __bf16* __restrict__ hbf, __bf16* __restrict__ wbuf)
{
    const int tid = threadIdx.x;
    const int bid = blockIdx.x;
    if (bid < 6144) {
        const long base = ((long)bid * 256 + tid) * 8;
        f32x4 a = *(const f32x4*)(hidden + base);
        f32x4 b = *(const f32x4*)(hidden + base + 4);
        bfx8 o;
        #pragma unroll
        for (int j = 0; j < 4; ++j) { o[j] = (__bf16)a[j]; o[4 + j] = (__bf16)b[j]; }
        *(bfx8*)(hbf + base) = o;
    } else {
        const long e = ((long)(bid - 6144) * 256 + tid) * 8;
        const int kind = (int)(e / WROWS_);
        const float* src = kind == 0 ? qw : kind == 1 ? kw : kind == 2 ? vw : ow;
        const long off = e - (long)kind * WROWS_;
        f32x4 a = *(const f32x4*)(src + off);
        f32x4 b = *(const f32x4*)(src + off + 4);
        bfx8 o;
        #pragma unroll
        for (int j = 0; j < 4; ++j) { o[j] = (__bf16)a[j]; o[4 + j] = (__bf16)b[j]; }
        *(bfx8*)(wbuf + e) = o;
    }
}

// ---------------------------------------------------------------------------
// Fused QKV GEMM. 128x128 tile, BK=64, swizzled global_load_lds staging.
// (unchanged)
// ---------------------------------------------------------------------------
__global__ __launch_bounds__(512, 4) void qkv_gemm(
    const __bf16* __restrict__ hbf, const __bf16* __restrict__ wbuf,
    const float* __restrict__ qb, const float* __restrict__ kb,
    const float* __restrict__ vb,
    __bf16* __restrict__ qo, __bf16* __restrict__ ko, __bf16* __restrict__ vto)
{
    __shared__ __bf16 smem[18432];      // 36864 B: As|Bs in [0,16384), Ts all
    __bf16* As = smem;                  // 8192 elems
    __bf16* Bs = smem + 8192;           // 8192 elems
    __bf16* Ts = smem;                  // epilogue: 8 waves x 2304 elems

    const int bid  = blockIdx.x;
    const int xcd  = bid & 7;
    const int slot = bid >> 3;          // 0..287
    const int xx   = slot >> 4;         // 0..17  (n-tile / weight panel)
    const int yy   = xcd * 16 + (slot & 15);   // 0..127 (m-tile)

    const int tid  = threadIdx.x;
    const int lane = tid & 63, wid = tid >> 6;
    const int quad = lane >> 4, l16 = lane & 15;
    const int n0g = xx * 128;
    const int m0  = yy * 128;
    const int wm = (wid & 3) * 32;      // s-slice (4)
    const int wn = (wid >> 2) * 64;     // d-slice (2)
    const int kind = xx / 6;            // 0=Q,1=K,2=V
    const int nl0  = n0g - kind * 768;

    // acc: Q/K -> [dt][st] flat dt*2+st ; V -> [st][dt] flat st*4+dt
    f32x4 acc[8];
    #pragma unroll
    for (int i = 0; i < 8; ++i)
        #pragma unroll
        for (int r = 0; r < 4; ++r) acc[i][r] = 0.0f;

    const int drow = lane >> 3;
    const int dcol = ((lane & 7) ^ (drow & 7)) * 8;
    const __bf16* Ag0 = hbf  + (long)(m0  + drow) * H_ + dcol;
    const __bf16* Bg0 = wbuf + (long)(n0g + drow) * H_ + dcol;
    const int swz = (l16 & 7);

    for (int kt = 0; kt < 12; ++kt) {
        __syncthreads();
        const int k0 = kt * 64;
        #pragma unroll
        for (int c = 0; c < 2; ++c) {
            const int cc = wid * 2 + c;       // chunk 0..15 (8 rows each)
            async_cp16(Ag0 + (long)cc * 8 * H_ + k0, As + cc * 512);
            async_cp16(Bg0 + (long)cc * 8 * H_ + k0, Bs + cc * 512);
        }
        __syncthreads();
        #pragma unroll
        for (int ks = 0; ks < 2; ++ks) {
            const int coff = ((ks * 4 + quad) ^ swz) * 8;
            bfx8 af[2], bb[4];
            #pragma unroll
            for (int t = 0; t < 2; ++t)
                af[t] = *(const bfx8*)(As + (wm + t * 16 + l16) * 64 + coff);
            #pragma unroll
            for (int t = 0; t < 4; ++t)
                bb[t] = *(const bfx8*)(Bs + (wn + t * 16 + l16) * 64 + coff);
            if (kind < 2) {
                #pragma unroll
                for (int dt = 0; dt < 4; ++dt)
                    #pragma unroll
                    for (int st = 0; st < 2; ++st)
                        acc[dt * 2 + st] = MFMA(bb[dt], af[st], acc[dt * 2 + st]);
            } else {
                #pragma unroll
                for (int st = 0; st < 2; ++st)
                    #pragma unroll
                    for (int dt = 0; dt < 4; ++dt)
                        acc[st * 4 + dt] = MFMA(af[st], bb[dt], acc[st * 4 + dt]);
            }
        }
    }

    __syncthreads();                    // As/Bs dead -> Ts reuse safe
    const int b  = m0 >> 10;
    const int hq = (nl0 + wn) >> 6;
    const int s_base = (m0 & 1023) + wm;

    if (kind < 2) {
        __bf16* Tw = Ts + wid * 2304;   // 32 x 72 tile [s][d]
        const float* bias = (kind == 0) ? qb : kb;
        __bf16* outp = (kind == 0) ? qo : ko;
        // acc[dt*2+st]: row=d=dt*16+quad*4+r, col=s=st*16+l16
        #pragma unroll
        for (int dt = 0; dt < 4; ++dt) {
            f32x4 bv = *(const f32x4*)(bias + nl0 + wn + dt * 16 + quad * 4);
            #pragma unroll
            for (int st = 0; st < 2; ++st) {
                bfx4 pk;
                #pragma unroll
                for (int r = 0; r < 4; ++r)
                    pk[r] = (__bf16)(acc[dt * 2 + st][r] + bv[r]);
                *(bfx4*)(Tw + (st * 16 + l16) * 72 + dt * 16 + quad * 4) = pk;
            }
        }
        __bf16* op = outp + ((((long)(b * NH_ + hq)) << 10) + s_base) * HD_;
        const int srow = lane >> 3, c8 = (lane & 7) * 8;
        #pragma unroll
        for (int i = 0; i < 4; ++i) {
            const int row = i * 8 + srow;                     // 0..31
            bfx8 vv = *(const bfx8*)(Tw + row * 72 + c8);
            *(bfx8*)(op + row * HD_ + c8) = vv;               // 1KB linear/instr
        }
    } else {
        __bf16* Tw = Ts + wid * 2304;   // 64 x 36 tile [d][s]
        // acc[st*4+dt]: row=s=st*16+quad*4+r, col=d=dt*16+l16
        #pragma unroll
        for (int dt = 0; dt < 4; ++dt) {
            const float bv = vb[nl0 + wn + dt * 16 + l16];
            #pragma unroll
            for (int st = 0; st < 2; ++st) {
                bfx4 pk;
                #pragma unroll
                for (int r = 0; r < 4; ++r)
                    pk[r] = (__bf16)(acc[st * 4 + dt][r] + bv);
                *(bfx4*)(Tw + (dt * 16 + l16) * 36 + st * 16 + quad * 4) = pk;
            }
        }
        __bf16* op = vto + (((long)(b * NH_ + hq) * HD_) << 10);
        #pragma unroll
        for (int i = 0; i < 4; ++i) {
            const int d = i * 16 + (lane >> 2);
            const int s8 = (lane & 3) * 8;
            bfx8 vv = *(const bfx8*)(Tw + d * 36 + s8);
            *(bfx8*)(op + ((long)d << 10) + s_base + s8) = vv;
        }
    }
}

// ---------------------------------------------------------------------------
// Attention, S^T formulation.
//  - 64-key K/V tiles, double-buffered: DMA for kt+1 issued right after the
//    barrier, compute on buf[kt&1]; the per-wave vmcnt(0) drain at the next
//    barrier lands after a full compute phase (DMA hidden under MFMA).
//  - Ps 32x32 per wave, 16B-slot XOR swizzle with row hash (l16>>1)&3:
//    8-lane b128 read groups cover all 32 banks exactly once (conflict-free);
//    16-lane b64 write groups are 2-way (free). NOTE: row hash must be
//    (l16>>1)&3, NOT l16&3 — bank parity is carried by l16&1, so l16&3
//    aliased rows r and r+4 (4-way conflicts, round-1 regression).
//  - launch_bounds(512,4): VGPR cap 128. (512,6) capped at ~85 and SPILLED
//    -> 900 MB/dispatch scratch traffic, MfmaUtil 8%. Occupancy stays at
//    2 blocks/CU; the double-buffer makes up the latency-hiding instead.
// ---------------------------------------------------------------------------
__global__ __launch_bounds__(512, 4) void attn_kernel(
    const __bf16* __restrict__ q, const __bf16* __restrict__ k,
    const __bf16* __restrict__ vT, const float* __restrict__ mask,
    __bf16* __restrict__ ctx)
{
    __shared__ __bf16 Ks[2][4096];      // [buf][64 keys x 64 d]    16 KB
    __shared__ __bf16 Vs[2][4096];      // [buf][64 d x 64 keys]    16 KB
    __shared__ __bf16 Ps[8][1024];      // per-wave [32 q][32 k] swz 16 KB
    __shared__ float  Ms[1024];         // mask*log2e - SMAX          4 KB

    const int tid  = threadIdx.x;
    const int lane = tid & 63, wid = tid >> 6;
    const int quad = lane >> 4, l16 = lane & 15;
    const int qc = blockIdx.x, h = blockIdx.y, b = blockIdx.z;

    const long base = ((long)(b * NH_ + h)) << 16;   // * S_ * HD_
    const __bf16* qh = q  + base;
    const __bf16* kh = k  + base;
    const __bf16* vh = vT + base;
    const float*  mb = mask + b * S_;

    Ms[tid]       = mb[tid]       * LOG2E - SMAX;
    Ms[tid + 512] = mb[tid + 512] * LOG2E - SMAX;

    const int qrow_base = qc * 256 + wid * 32;
    bfx8 qf[2][2];
    #pragma unroll
    for (int nt = 0; nt < 2; ++nt)
        #pragma unroll
        for (int kk = 0; kk < 2; ++kk)
            qf[nt][kk] = *(const bfx8*)(qh + (qrow_base + nt * 16 + l16) * HD_ +
                                        kk * 32 + quad * 8);

    f32x4 o[4][2];
    f32x4 lacc[2];
    #pragma unroll
    for (int mt = 0; mt < 4; ++mt)
        #pragma unroll
        for (int nt = 0; nt < 2; ++nt)
            #pragma unroll
            for (int r = 0; r < 4; ++r) o[mt][nt][r] = 0.0f;
    #pragma unroll
    for (int nt = 0; nt < 2; ++nt)
        #pragma unroll
        for (int r = 0; r < 4; ++r) lacc[nt][r] = 0.0f;

    // staging geometry: chunk = wid (1KB), 8 rows/chunk, row-local swizzle
    const int r8  = lane >> 3;                 // row within chunk (0..7)
    const int c8  = ((lane & 7) ^ r8) * 8;     // pre-swizzled 16B col group
    const int swz = l16 & 7;
    const int swz2 = (l16 >> 1) & 3;           // Ps row hash (16B slots)

    // prologue: stage kt=0 into buf 0
    async_cp16(kh + (long)(wid * 8 + r8) * HD_ + c8, &Ks[0][wid * 512]);
    async_cp16(vh + (long)(wid * 8 + r8) * S_  + c8, &Vs[0][wid * 512]);

    for (int kt = 0; kt < 16; ++kt) {
        __syncthreads();                // per-wave vmcnt(0): buf[kt&1] ready
        const __bf16* Kb = Ks[kt & 1];
        const __bf16* Vb = Vs[kt & 1];
        if (kt < 15) {                  // prefetch kt+1 into the other buffer
            const int kn = kt + 1;
            async_cp16(kh + (long)(kn * 64 + wid * 8 + r8) * HD_ + c8,
                       &Ks[kn & 1][wid * 512]);
            async_cp16(vh + (long)(wid * 8 + r8) * S_ + kn * 64 + c8,
                       &Vs[kn & 1][wid * 512]);
        }

        #pragma unroll
        for (int ph = 0; ph < 2; ++ph) {        // 32-key half
            #pragma unroll
            for (int tl = 0; tl < 2; ++tl) {    // 16-key score tile
                const int t = ph * 2 + tl;
                f32x4 sc[2];
                #pragma unroll
                for (int nt = 0; nt < 2; ++nt)
                    #pragma unroll
                    for (int r = 0; r < 4; ++r) sc[nt][r] = 0.0f;
                #pragma unroll
                for (int kk = 0; kk < 2; ++kk) {
                    bfx8 kf = *(const bfx8*)(Kb + (t * 16 + l16) * 64 +
                                             ((kk * 4 + quad) ^ swz) * 8);
                    #pragma unroll
                    for (int nt = 0; nt < 2; ++nt)
                        sc[nt] = MFMA(kf, qf[nt][kk], sc[nt]);
                }
                const f32x4 mv = *(const f32x4*)(&Ms[kt * 64 + t * 16 + quad * 4]);
                // 16B key-group log16 = tl*2+(quad>>1); phys = log16 ^ swz2
                const int pslot = ((tl * 2 + (quad >> 1)) ^ swz2) * 8 +
                                  (quad & 1) * 4;
                #pragma unroll
                for (int nt = 0; nt < 2; ++nt) {
                    f32x4 p; bfx4 pb;
                    #pragma unroll
                    for (int r = 0; r < 4; ++r)
                        p[r] = fast_exp2(sc[nt][r] * C1 + mv[r]);
                    lacc[nt] += p;
                    #pragma unroll
                    for (int r = 0; r < 4; ++r) pb[r] = (__bf16)p[r];
                    *(bfx4*)(&Ps[wid][(nt * 16 + l16) * 32 + pslot]) = pb;
                }
            }
            // PV for this 32-key half: 16B key group = quad, phys = quad^swz2
            bfx8 pf[2];
            const int prslot = (quad ^ swz2) * 8;
            #pragma unroll
            for (int nt = 0; nt < 2; ++nt)
                pf[nt] = *(const bfx8*)(&Ps[wid][(nt * 16 + l16) * 32 + prslot]);
            const int vcg = (ph * 4 + quad) ^ swz;
            #pragma unroll
            for (int mt = 0; mt < 4; ++mt) {
                bfx8 vf = *(const bfx8*)(Vb + (mt * 16 + l16) * 64 + vcg * 8);
                #pragma unroll
                for (int nt = 0; nt < 2; ++nt)
                    o[mt][nt] = MFMA(vf, pf[nt], o[mt][nt]);
            }
        }
    }

    float linv[2];
    #pragma unroll
    for (int nt = 0; nt < 2; ++nt) {
        float s = lacc[nt][0] + lacc[nt][1] + lacc[nt][2] + lacc[nt][3];
        s += __shfl_xor(s, 16);
        s += __shfl_xor(s, 32);
        linv[nt] = 1.0f / s;
    }

    #pragma unroll
    for (int nt = 0; nt < 2; ++nt) {
        #pragma unroll
        for (int mt = 0; mt < 4; ++mt) {
            bfx4 ov;
            #pragma unroll
            for (int r = 0; r < 4; ++r)
                ov[r] = (__bf16)(o[mt][nt][r] * linv[nt]);
            const int qrow = qrow_base + nt * 16 + l16;
            *(bfx4*)(ctx + ((long)(b << 10) + qrow) * H_ + h * HD_ +
                     mt * 16 + quad * 4) = ov;
        }
    }
}

// ---------------------------------------------------------------------------
// Output projection + residual. 8 waves x (32m x 64n), XCD-chunked map.
// ---------------------------------------------------------------------------
__global__ __launch_bounds__(512, 4) void out_gemm(
    const __bf16* __restrict__ ctx, const __bf16* __restrict__ wbuf,
    const float* __restrict__ ob, const float* __restrict__ hidden,
    float* __restrict__ xres)
{
    __shared__ __bf16 As[128 * 64];
    __shared__ __bf16 Bs[128 * 64];

    const int bid  = blockIdx.x;
    const int xcd  = bid & 7;
    const int slot = bid >> 3;          // 0..95
    const int xx   = slot >> 4;         // 0..5
    const int yy   = xcd * 16 + (slot & 15);

    const int tid  = threadIdx.x;
    const int lane = tid & 63, wid = tid >> 6;
    const int quad = lane >> 4, l16 = lane & 15;
    const int n0 = xx * 128;
    const int m0 = yy * 128;
    const int wm = (wid & 3) * 32;
    const int wn = (wid >> 2) * 64;

    f32x4 acc[2][4];
    #pragma unroll
    for (int i = 0; i < 2; ++i)
        #pragma unroll
        for (int j = 0; j < 4; ++j)
            #pragma unroll
            for (int r = 0; r < 4; ++r) acc[i][j][r] = 0.0f;

    const int drow = lane >> 3;
    const int dcol = ((lane & 7) ^ (drow & 7)) * 8;
    const __bf16* Ag0 = ctx  + (long)(m0 + drow) * H_ + dcol;
    const __bf16* Bg0 = wbuf + (long)(3 * 768 + n0 + drow) * H_ + dcol;
    const int swz = (l16 & 7);

    for (int kt = 0; kt < 12; ++kt) {
        __syncthreads();
        const int k0 = kt * 64;
        #pragma unroll
        for (int c = 0; c < 2; ++c) {
            const int cc = wid * 2 + c;
            async_cp16(Ag0 + (long)cc * 8 * H_ + k0, As + cc * 512);
            async_cp16(Bg0 + (long)cc * 8 * H_ + k0, Bs + cc * 512);
        }
        __syncthreads();
        #pragma unroll
        for (int ks = 0; ks < 2; ++ks) {
            const int coff = ((ks * 4 + quad) ^ swz) * 8;
            bfx8 af[2], bb[4];
            #pragma unroll
            for (int t = 0; t < 2; ++t)
                af[t] = *(const bfx8*)(As + (wm + t * 16 + l16) * 64 + coff);
            #pragma unroll
            for (int t = 0; t < 4; ++t)
                bb[t] = *(const bfx8*)(Bs + (wn + t * 16 + l16) * 64 + coff);
            #pragma unroll
            for (int mt = 0; mt < 2; ++mt)
                #pragma unroll
                for (int nt = 0; nt < 4; ++nt)
                    acc[mt][nt] = MFMA(af[mt], bb[nt], acc[mt][nt]);
        }
    }

    #pragma unroll
    for (int nt = 0; nt < 4; ++nt) {
        const int n = n0 + wn + nt * 16 + l16;
        const float bv = ob[n];
        #pragma unroll
        for (int mt = 0; mt < 2; ++mt) {
            #pragma unroll
            for (int r = 0; r < 4; ++r) {
                const int m = m0 + wm + mt * 16 + quad * 4 + r;
                const long idx = (long)m * H_ + n;
                xres[idx] = acc[mt][nt][r] + bv + hidden[idx];
            }
        }
    }
}

// ---------------------------------------------------------------------------
// LayerNorm over H=768, wave per row
// ---------------------------------------------------------------------------
__global__ __launch_bounds__(256) void ln_kernel(
    const float* __restrict__ xres, const float* __restrict__ gamma,
    const float* __restrict__ beta, float* __restrict__ out)
{
    const int tid = threadIdx.x, lane = tid & 63, wid = tid >> 6;
    const long row = (long)blockIdx.x * 4 + wid;
    const float* xr = xres + row * H_;

    f32x4 xv[3];
    float sum = 0.0f, sumsq = 0.0f;
    #pragma unroll
    for (int c = 0; c < 3; ++c) {
        xv[c] = *(const f32x4*)(xr + c * 256 + lane * 4);
        #pragma unroll
        for (int j = 0; j < 4; ++j) { sum += xv[c][j]; sumsq += xv[c][j] * xv[c][j]; }
    }
    #pragma unroll
    for (int off = 1; off < 64; off <<= 1) {
        sum   += __shfl_xor(sum, off);
        sumsq += __shfl_xor(sumsq, off);
    }
    const float mean = sum * (1.0f / 768.0f);
    const float var  = sumsq * (1.0f / 768.0f) - mean * mean;
    const float rstd = rsqrtf(var + 1e-12f);

    float* orow = out + row * H_;
    #pragma unroll
    for (int c = 0; c < 3; ++c) {
        f32x4 g  = *(const f32x4*)(gamma + c * 256 + lane * 4);
        f32x4 bt = *(const f32x4*)(beta  + c * 256 + lane * 4);
        f32x4 ov;
        #pragma unroll
        for (int j = 0; j < 4; ++j) ov[j] = (xv[c][j] - mean) * rstd * g[j] + bt[j];
        *(f32x4*)(orow + c * 256 + lane * 4) = ov;
    }
}

extern "C" void kernel_launch(void* const* d_in, const int* in_sizes, int n_in,
                              void* d_out, int out_size, void* d_ws, size_t ws_size,
                              hipStream_t stream)
{
    const float* hidden = (const float*)d_in[0];
    const float* mask   = (const float*)d_in[1];
    const float* qw = (const float*)d_in[2];
    const float* qb = (const float*)d_in[3];
    const float* kw = (const float*)d_in[4];
    const float* kb = (const float*)d_in[5];
    const float* vw = (const float*)d_in[6];
    const float* vb = (const float*)d_in[7];
    const float* ow = (const float*)d_in[8];
    const float* ob = (const float*)d_in[9];
    const float* gamma = (const float*)d_in[10];
    const float* beta  = (const float*)d_in[11];
    float* out = (float*)d_out;

    // ws layout (96 MB): [0,24) hbf->ctx alias; [24,48) q; [48,72) k; [72,96) vt
    // xres fp32 aliases [24,72). wbuf bf16 weights live in d_out until ln.
    char* ws = (char*)d_ws;
    const size_t SZB = (size_t)BS_ * H_ * 2;     // 25,165,824 B per bf16 buffer
    __bf16* hbf  = (__bf16*)ws;
    __bf16* qws  = (__bf16*)(ws + SZB);
    __bf16* kws  = (__bf16*)(ws + 2 * SZB);
    __bf16* vtws = (__bf16*)(ws + 3 * SZB);
    __bf16* cws  = hbf;                          // ctx aliases hbf
    float*  xres = (float*)(ws + SZB);           // aliases q,k
    __bf16* wbuf = (__bf16*)d_out;               // scratch inside output buffer

    precast<<<dim3(7296), 256, 0, stream>>>(hidden, qw, kw, vw, ow, hbf, wbuf);
    qkv_gemm<<<dim3(2304), 512, 0, stream>>>(hbf, wbuf, qb, kb, vb,
                                             qws, kws, vtws);
    attn_kernel<<<dim3(4, 12, 16), 512, 0, stream>>>(qws, kws, vtws, mask, cws);
    out_gemm<<<dim3(768), 512, 0, stream>>>(cws, wbuf, ob, hidden, xres);
    ln_kernel<<<dim3(4096), 256, 0, stream>>>(xres, gamma, beta, out);
}